// Round 1
// baseline (127.461 us; speedup 1.0000x reference)
//
#include <hip/hip_runtime.h>
#include <hip/hip_bf16.h>

#define N_ATOMS   200000
#define D_IN      256
#define D_OUT     256
#define N_SPECIES 4
#define N_STRUCT  2000

typedef __attribute__((ext_vector_type(8))) short bf16x8;
typedef __attribute__((ext_vector_type(4))) float f32x4;

__device__ inline unsigned short f2bf(float f) {
    unsigned int u = __float_as_uint(f);
    unsigned int r = (u + 0x7fffu + ((u >> 16) & 1u)) >> 16;   // RNE
    return (unsigned short)r;
}
__device__ inline float bf2f(unsigned short us) {
    return __uint_as_float(((unsigned int)us) << 16);
}

// ---- ws layout (bytes) ----
// 0        : Wt bf16 [4][4][256][64]       = 524288
// 524288   : perm int[200000]              = 800000  (ends 1324288)
// 1324288  : totals int[4]
// then base[5], running[4], tilesBefore[5]

// K1: convert + transpose W -> Wt[s][kb][n][kp]  (B pre-tiled per K-step, [n][k'] layout)
__global__ void k_wt(const float* __restrict__ W, unsigned short* __restrict__ Wt) {
    int k = blockIdx.x;        // 0..255
    int n = threadIdx.x;       // 0..255
    for (int s = 0; s < N_SPECIES; ++s) {
        float v = W[((size_t)s * 256 + k) * 256 + n];
        Wt[(((size_t)(s * 4 + (k >> 6)) * 256 + n) * 64) + (k & 63)] = f2bf(v);
    }
}

// K2: species histogram
__global__ void k_hist(const int* __restrict__ spec, int* __restrict__ totals) {
    __shared__ int h[N_SPECIES];
    int t = threadIdx.x;
    if (t < N_SPECIES) h[t] = 0;
    __syncthreads();
    int a = blockIdx.x * 256 + t;
    if (a < N_ATOMS) atomicAdd(&h[spec[a]], 1);
    __syncthreads();
    if (t < N_SPECIES && h[t]) atomicAdd(&totals[t], h[t]);
}

// K3: bases + running counters + tile table (1 thread)
__global__ void k_meta(const int* __restrict__ totals, int* __restrict__ base,
                       int* __restrict__ running, int* __restrict__ tilesBefore) {
    if (threadIdx.x == 0) {
        int acc = 0, tb = 0;
        for (int s = 0; s < N_SPECIES; ++s) {
            base[s] = acc; running[s] = acc; tilesBefore[s] = tb;
            acc += totals[s];
            tb  += (totals[s] + 63) >> 6;
        }
        base[N_SPECIES] = acc; tilesBefore[N_SPECIES] = tb;
    }
}

// K4: scatter atoms into species-grouped perm (chunk-local order preserved)
__global__ void k_scatter(const int* __restrict__ spec, int* __restrict__ running,
                          int* __restrict__ perm) {
    __shared__ int ssp[256];
    __shared__ int cnt[N_SPECIES];
    __shared__ int cbase[N_SPECIES];
    int t = threadIdx.x;
    int a = blockIdx.x * 256 + t;
    int s = (a < N_ATOMS) ? spec[a] : -1;
    ssp[t] = s;
    if (t < N_SPECIES) cnt[t] = 0;
    __syncthreads();
    if (s >= 0) atomicAdd(&cnt[s], 1);
    __syncthreads();
    if (t < N_SPECIES && cnt[t] > 0) cbase[t] = atomicAdd(&running[t], cnt[t]);
    __syncthreads();
    if (s >= 0) {
        int r = 0;
        for (int j = 0; j < t; ++j) r += (ssp[j] == s);
        perm[cbase[s] + r] = a;
    }
}

// K5: grouped GEMM (64 atoms x 256 cols / block) + fused bias + segment reduce
__global__ __launch_bounds__(256) void k_gemm(
        const float* __restrict__ x, const float* __restrict__ bias,
        const int* __restrict__ sidx_g, const int* __restrict__ perm,
        const int* __restrict__ base, const int* __restrict__ totals,
        const int* __restrict__ tilesBefore, const unsigned short* __restrict__ Wt,
        float* __restrict__ out) {

    __shared__ __align__(16) unsigned short smem[64 * 72 + 256 * 72]; // 46080 B
    unsigned short* Al = smem;            // [64][72] bf16 (stride 144 B)
    unsigned short* Bl = smem + 64 * 72;  // [256][72] bf16, [n][k'] layout
    unsigned short* Yl = smem;            // reused: [64][264] bf16 = 33792 B
    __shared__ int atomRow[64];
    __shared__ int sidx[64];

    int bid = blockIdx.x;
    if (bid >= tilesBefore[N_SPECIES]) return;
    int s = 0;
    while (bid >= tilesBefore[s + 1]) ++s;
    int r0    = (bid - tilesBefore[s]) * 64;
    int rows  = min(64, totals[s] - r0);
    int pbase = base[s] + r0;

    int t    = threadIdx.x;
    int wave = t >> 6;
    int lane = t & 63;
    int l15  = lane & 15;
    int l4   = lane >> 4;

    if (t < 64) {
        int at = (t < rows) ? perm[pbase + t] : -1;
        atomRow[t] = at;
        sidx[t]    = (at >= 0) ? sidx_g[at] : -1;
    }

    f32x4 acc[4][4];
#pragma unroll
    for (int m = 0; m < 4; ++m)
#pragma unroll
        for (int n = 0; n < 4; ++n) acc[m][n] = (f32x4){0.f, 0.f, 0.f, 0.f};

    for (int kb = 0; kb < 4; ++kb) {
        __syncthreads();
        // stage A: 64 rows x 64 k (gathered), fp32 -> bf16
        {
            int row = t >> 2, q = t & 3;
            int at = atomRow[row];
            unsigned short* dst = Al + row * 72 + q * 16;
            if (at >= 0) {
                const float* src = x + (size_t)at * 256 + kb * 64 + q * 16;
#pragma unroll
                for (int i = 0; i < 4; ++i) {
                    float4 v = *(const float4*)(src + i * 4);
                    ushort4 u;
                    u.x = f2bf(v.x); u.y = f2bf(v.y); u.z = f2bf(v.z); u.w = f2bf(v.w);
                    *(ushort4*)(dst + i * 4) = u;
                }
            } else {
                ushort4 z = {0, 0, 0, 0};
#pragma unroll
                for (int i = 0; i < 4; ++i) *(ushort4*)(dst + i * 4) = z;
            }
        }
        // stage B: contiguous 32 KB block -> [n][72]
        {
            const unsigned short* wsrc = Wt + (size_t)(s * 4 + kb) * 256 * 64;
#pragma unroll
            for (int i = 0; i < 8; ++i) {
                int c = i * 256 + t;                 // 16-byte chunk id
                int4 v = *(const int4*)(wsrc + c * 8);
                int n  = c >> 3, kp = (c & 7) * 8;
                *(int4*)(Bl + n * 72 + kp) = v;
            }
        }
        __syncthreads();

#pragma unroll
        for (int ks = 0; ks < 2; ++ks) {
            int ko = ks * 32 + l4 * 8;
            bf16x8 af[4], bfr[4];
#pragma unroll
            for (int m = 0; m < 4; ++m)
                af[m] = *(const bf16x8*)(Al + (m * 16 + l15) * 72 + ko);
#pragma unroll
            for (int n = 0; n < 4; ++n)
                bfr[n] = *(const bf16x8*)(Bl + (wave * 64 + n * 16 + l15) * 72 + ko);
#pragma unroll
            for (int m = 0; m < 4; ++m)
#pragma unroll
                for (int n = 0; n < 4; ++n)
                    acc[m][n] = __builtin_amdgcn_mfma_f32_16x16x32_bf16(
                        af[m], bfr[n], acc[m][n], 0, 0, 0);
        }
    }

    // bias
    float bv[4];
#pragma unroll
    for (int n = 0; n < 4; ++n)
        bv[n] = bias[s * 256 + wave * 64 + n * 16 + l15];

    __syncthreads();
    // stage y (bf16) into reused LDS
#pragma unroll
    for (int m = 0; m < 4; ++m)
#pragma unroll
        for (int n = 0; n < 4; ++n) {
            int col = wave * 64 + n * 16 + l15;
#pragma unroll
            for (int r = 0; r < 4; ++r) {
                int row = m * 16 + l4 * 4 + r;
                Yl[row * 264 + col] = f2bf(acc[m][n][r] + bv[n]);
            }
        }
    __syncthreads();

    // per-column run-length segment reduce -> atomicAdd
    {
        int col = t;
        float run = 0.f;
        int cur = -2;
#pragma unroll 1
        for (int r = 0; r < 64; ++r) {
            int sr = sidx[r];
            if (sr != cur) {
                if (cur >= 0) atomicAdd(&out[(size_t)cur * 256 + col], run);
                run = 0.f;
                cur = sr;
            }
            if (sr >= 0) run += bf2f(Yl[r * 264 + col]);
        }
        if (cur >= 0) atomicAdd(&out[(size_t)cur * 256 + col], run);
    }
}

extern "C" void kernel_launch(void* const* d_in, const int* in_sizes, int n_in,
                              void* d_out, int out_size, void* d_ws, size_t ws_size,
                              hipStream_t stream) {
    const float* x    = (const float*)d_in[0];
    const float* W    = (const float*)d_in[1];
    const float* b    = (const float*)d_in[2];
    const int* spec   = (const int*)d_in[3];
    const int* sidx   = (const int*)d_in[4];
    float* out        = (float*)d_out;

    char* ws = (char*)d_ws;
    unsigned short* Wt = (unsigned short*)ws;               // 524288 B
    int* perm   = (int*)(ws + 524288);                      // 800000 B
    int* totals = (int*)(ws + 1324288);                     // 4
    int* base        = totals + 4;                          // 5
    int* running     = base + 5;                            // 4
    int* tilesBefore = running + 4;                         // 5

    hipMemsetAsync(d_out, 0, (size_t)out_size * sizeof(float), stream);
    hipMemsetAsync(totals, 0, 4 * sizeof(int), stream);

    k_wt     <<<256, 256, 0, stream>>>(W, Wt);
    k_hist   <<<(N_ATOMS + 255) / 256, 256, 0, stream>>>(spec, totals);
    k_meta   <<<1, 64, 0, stream>>>(totals, base, running, tilesBefore);
    k_scatter<<<(N_ATOMS + 255) / 256, 256, 0, stream>>>(spec, running, perm);
    k_gemm   <<<(N_ATOMS / 64) + N_SPECIES, 256, 0, stream>>>(
        x, b, sidx, perm, base, totals, tilesBefore, Wt, out);
}